// Round 1
// baseline (1610.392 us; speedup 1.0000x reference)
//
#include <hip/hip_runtime.h>
#include <math.h>

#define BATCH 16384
#define NSMAX 8
#define LOG2PI_F 1.8378770664093453f
#define LOG4_F 1.3862943611198906f

// wave-uniform lane broadcast via v_readlane (no LDS traffic)
__device__ __forceinline__ float bcast(float v, int l) {
    return __uint_as_float(__builtin_amdgcn_readlane(__float_as_uint(v), (unsigned)l));
}
__device__ __forceinline__ float redsum64(float v) {
    v += __shfl_xor(v, 1);
    v += __shfl_xor(v, 2);
    v += __shfl_xor(v, 4);
    v += __shfl_xor(v, 8);
    v += __shfl_xor(v, 16);
    v += __shfl_xor(v, 32);
    return v;
}
// select a[l] from 8 replicated registers, l = lane index bits 0..2
__device__ __forceinline__ float sel8(float a0,float a1,float a2,float a3,
                                      float a4,float a5,float a6,float a7,int l){
    float m01=(l&1)?a1:a0, m23=(l&1)?a3:a2, m45=(l&1)?a5:a4, m67=(l&1)?a7:a6;
    float n03=(l&2)?m23:m01, n47=(l&2)?m67:m45;
    return (l&4)?n47:n03;
}
__device__ __forceinline__ float softplusf(float v){
    return fmaxf(v, 0.f) + log1pf(expf(-fabsf(v)));
}
__device__ __forceinline__ float sigmoidf(float v){ return 1.f/(1.f+expf(-v)); }

// ---------------------------------------------------------------------------
// K1: per-element MLP (z0) + 8 Adam steps. Stores z0, per-step xn trajectory,
// and atomically accumulates per-step loss sums.
// Block = 512 threads = 8 waves = 8 batch elements. LDS ~57.9KB -> 2 blk/CU.
// ---------------------------------------------------------------------------
__global__ __launch_bounds__(512) void k_adam(
    const float* __restrict__ visual, const float* __restrict__ vel,
    const float* __restrict__ tl, const float* __restrict__ tls,
    const float* __restrict__ goal, const float* __restrict__ bs,
    const float* __restrict__ Wm1, const float* __restrict__ bm1,
    const float* __restrict__ Wm2, const float* __restrict__ bm2,
    const float* __restrict__ Wm3, const float* __restrict__ bm3,
    const float* __restrict__ wih, const float* __restrict__ whh,
    const float* __restrict__ bih, const float* __restrict__ bhh,
    const float* __restrict__ Wl1, const float* __restrict__ bl1,
    const float* __restrict__ Wl2, const float* __restrict__ bl2,
    const int*  __restrict__ nsp,
    float* __restrict__ z0ws, float* __restrict__ traj, float* __restrict__ lossacc)
{
    __shared__ float smem[14472];
    const int tid  = threadIdx.x;
    const int lane = tid & 63;
    const int w    = tid >> 6;
    const int b    = blockIdx.x * 8 + w;

    // ================= MLP phase (z0) =================
    // phase A: Wm1 (133x64) + per-wave feature buffer
    for (int i = tid; i < 8512; i += 512) smem[i] = Wm1[i];
    float* sfeat = smem + 8512 + w * 136;
    sfeat[lane]      = visual[b*128 + lane];
    sfeat[64 + lane] = visual[b*128 + 64 + lane];
    if (lane < 3)  sfeat[128 + lane] = vel[b*3 + lane];
    if (lane == 3) sfeat[131] = tl[b];
    if (lane == 4) sfeat[132] = tls[b];
    __syncthreads();
    float acc = bm1[lane];
    for (int f = 0; f < 133; ++f) acc = fmaf(smem[f*64 + lane], sfeat[f], acc);
    float z1 = fmaxf(acc, 0.f);
    __syncthreads();
    for (int i = tid; i < 4096; i += 512) smem[i] = Wm2[i];
    __syncthreads();
    acc = bm2[lane];
    #pragma unroll 8
    for (int kk = 0; kk < 64; ++kk) acc = fmaf(smem[kk*64 + lane], bcast(z1, kk), acc);
    float z2 = fmaxf(acc, 0.f);
    __syncthreads();
    for (int i = tid; i < 4096; i += 512) smem[i] = Wm3[i];
    __syncthreads();
    acc = bm3[lane];
    #pragma unroll 8
    for (int kk = 0; kk < 64; ++kk) acc = fmaf(smem[kk*64 + lane], bcast(z2, kk), acc);
    float z0r = fmaxf(acc, 0.f);
    z0ws[(size_t)b*64 + lane] = z0r;
    __syncthreads();

    // ================= flow weights into LDS =================
    // wT[k][c], c = g*64+j, row stride 193: conflict-free for forward
    // (fixed k, lane=j) AND backward (fixed c, lane=k) access.
    float* swT  = smem;            // 64*193 = 12352
    float* swl1 = smem + 12352;    // 64*33  = 2112  -> 14464
    float* sred = smem + 14464;    // 8
    for (int i = tid; i < 12288; i += 512) {
        int k = i / 192, c = i - k*192;
        swT[k*193 + c] = whh[c*64 + k];
    }
    for (int i = tid; i < 2048; i += 512) {
        int k = i >> 5, c = i & 31;
        swl1[k*33 + c] = Wl1[i];
    }
    __syncthreads();

    // per-lane parameter registers
    const int il = lane & 31;
    float wr0 = wih[lane*2],       wr1 = wih[lane*2+1];
    float wu0 = wih[(64+lane)*2],  wu1 = wih[(64+lane)*2+1];
    float wn0 = wih[(128+lane)*2], wn1 = wih[(128+lane)*2+1];
    float br = bih[lane], bu = bih[64+lane], bn = bih[128+lane];
    float hr = bhh[lane], hu = bhh[64+lane], hn = bhh[128+lane];
    float w2a = Wl2[il*4], w2b = Wl2[il*4+1], w2c = Wl2[il*4+2], w2d = Wl2[il*4+3];
    float b1r = bl1[il];
    float b20 = bl2[0], b21 = bl2[1], b22 = bl2[2], b23 = bl2[3];
    float gk[4][2];
    #pragma unroll
    for (int kk = 0; kk < 4; ++kk) {
        gk[kk][0] = goal[(size_t)b*8 + kk*2];
        gk[kk][1] = goal[(size_t)b*8 + kk*2 + 1];
    }
    float x[4][2];
    #pragma unroll
    for (int t = 0; t < 4; ++t) { x[t][0] = bs[t*2]; x[t][1] = bs[t*2+1]; }
    float xd = (lane < 8) ? bs[lane] : 0.f;   // lane l<8 owns component l
    float am = 0.f, av = 0.f;                 // distributed Adam state
    float p1 = 1.f, p2 = 1.f;
    int ns = *nsp; if (ns > NSMAX) ns = NSMAX;

    for (int s = 0; s < ns; ++s) {
        // ---------- forward flow (save state for backward) ----------
        float zc = z0r;
        float zsv[4], rsv[4], usv[4], nsv[4], gsv[4], asv[4], scl[4][2];
        float y0 = 0.f, y1 = 0.f, sumls = 0.f;
        #pragma unroll
        for (int t = 0; t < 4; ++t) {
            float gir = fmaf(wr0, y0, fmaf(wr1, y1, br));
            float giu = fmaf(wu0, y0, fmaf(wu1, y1, bu));
            float gin = fmaf(wn0, y0, fmaf(wn1, y1, bn));
            float ghr = hr, ghu = hu, ghn = hn;
            #pragma unroll 8
            for (int kk = 0; kk < 64; ++kk) {
                float zk = bcast(zc, kk);
                const float* wp = swT + kk*193 + lane;
                ghr = fmaf(wp[0],   zk, ghr);
                ghu = fmaf(wp[64],  zk, ghu);
                ghn = fmaf(wp[128], zk, ghn);
            }
            float r = sigmoidf(gir + ghr);
            float u = sigmoidf(giu + ghu);
            float n = tanhf(fmaf(r, ghn, gin));
            zsv[t] = zc; rsv[t] = r; usv[t] = u; nsv[t] = n; gsv[t] = ghn;
            zc = fmaf(u, zc - n, n);          // (1-u)*n + u*z_prev
            // Wl1: all 64 lanes compute output i=il over full k range
            float pre = 0.f;
            #pragma unroll 8
            for (int kk = 0; kk < 64; ++kk)
                pre = fmaf(swl1[kk*33 + il], bcast(zc, kk), pre);
            float a = fmaxf(pre + b1r, 0.f);
            asv[t] = a;
            // Wl2: lanes 0..31 and 32..63 duplicate -> *0.5 after 64-lane sum
            float c0 = redsum64(a * w2a) * 0.5f + b20;
            float c1 = redsum64(a * w2b) * 0.5f + b21;
            float c2 = redsum64(a * w2c) * 0.5f + b22;
            float c3 = redsum64(a * w2d) * 0.5f + b23;
            float s0 = softplusf(c2) + 0.001f;
            float s1 = softplusf(c3) + 0.001f;
            scl[t][0] = s0; scl[t][1] = s1;
            sumls += logf(s0) + logf(s1);
            y0 += c0 + s0 * x[t][0];
            y1 += c1 + s1 * x[t][1];
        }
        // ---------- loss contribution ----------
        float sumx2 = 0.f;
        #pragma unroll
        for (int t = 0; t < 4; ++t) sumx2 += x[t][0]*x[t][0] + x[t][1]*x[t][1];
        float comp[4], mx = -1e30f;
        #pragma unroll
        for (int kk = 0; kk < 4; ++kk) {
            float d0 = y0 - gk[kk][0], d1 = y1 - gk[kk][1];
            comp[kk] = -0.5f*(d0*d0 + d1*d1) - LOG2PI_F;
            mx = fmaxf(mx, comp[kk]);
        }
        float se = 0.f, e[4];
        #pragma unroll
        for (int kk = 0; kk < 4; ++kk) { e[kk] = expf(comp[kk]-mx); se += e[kk]; }
        float lp = mx + logf(se) - LOG4_F;
        float c_elem = -0.5f*sumx2 - 4.f*LOG2PI_F - sumls + lp;
        if (lane == 0) sred[w] = c_elem;
        __syncthreads();
        if (tid == 0) {
            float t8 = 0.f;
            #pragma unroll
            for (int i = 0; i < 8; ++i) t8 += sred[i];
            atomicAdd(&lossacc[s], t8);
        }
        __syncthreads();
        // ---------- backward ----------
        float inv_se = 1.f / se;
        float yb0 = 0.f, yb1 = 0.f;
        #pragma unroll
        for (int kk = 0; kk < 4; ++kk) {
            float p = e[kk] * inv_se;
            yb0 += p * (gk[kk][0] - y0);
            yb1 += p * (gk[kk][1] - y1);
        }
        float zb = 0.f;
        float xbar[4][2];
        #pragma unroll
        for (int t = 3; t >= 0; --t) {
            float s0 = scl[t][0], s1 = scl[t][1];
            float sb0 = fmaf(yb0, x[t][0], -1.f/s0);
            float sb1 = fmaf(yb1, x[t][1], -1.f/s1);
            xbar[t][0] = fmaf(yb0, s0, -x[t][0]);
            xbar[t][1] = fmaf(yb1, s1, -x[t][1]);
            float sg0 = 1.f - expf(-(s0 - 0.001f));   // sigmoid(ls2)
            float sg1 = 1.f - expf(-(s1 - 0.001f));
            float l2 = sb0 * sg0, l3 = sb1 * sg1;
            float ab = w2a*yb0 + w2b*yb1 + w2c*l2 + w2d*l3;
            ab = (asv[t] > 0.f) ? ab : 0.f;
            float ztb = zb;
            #pragma unroll 8
            for (int i2 = 0; i2 < 32; ++i2)
                ztb = fmaf(swl1[lane*33 + i2], bcast(ab, i2), ztb);
            float u = usv[t], r = rsv[t], n = nsv[t], gh = gsv[t], zp = zsv[t];
            float nb = ztb * (1.f - u);
            float ub = ztb * (zp - n);
            float hb = ztb * u;
            float dn = nb * (1.f - n*n);
            float rb = dn * gh;
            float gnb = dn * r;
            float du = ub * u * (1.f - u);
            float dr = rb * r * (1.f - r);
            #pragma unroll 8
            for (int jj = 0; jj < 64; ++jj) {
                float brd = bcast(dr, jj);
                float bud = bcast(du, jj);
                float bnd = bcast(gnb, jj);
                const float* wp = swT + lane*193 + jj;
                hb = fmaf(wp[0],   brd, hb);
                hb = fmaf(wp[64],  bud, hb);
                hb = fmaf(wp[128], bnd, hb);
            }
            float px0 = dr*wr0 + du*wu0 + dn*wn0;
            float px1 = dr*wr1 + du*wu1 + dn*wn1;
            yb0 += redsum64(px0);
            yb1 += redsum64(px1);
            zb = hb;
        }
        // ---------- Adam update (lanes 0..7 own components) ----------
        float g = sel8(xbar[0][0], xbar[0][1], xbar[1][0], xbar[1][1],
                       xbar[2][0], xbar[2][1], xbar[3][0], xbar[3][1], lane)
                  * (-1.f / 16384.f);
        am = fmaf(0.9f,   am, 0.1f   * g);
        av = fmaf(0.999f, av, 0.001f * g * g);
        p1 *= 0.9f; p2 *= 0.999f;
        float mh = am / (1.f - p1);
        float vh = av / (1.f - p2);
        xd = xd - 0.1f * mh / (sqrtf(vh) + 1e-8f);
        if (lane < 8) traj[((size_t)b*NSMAX + s)*8 + lane] = xd;
        #pragma unroll
        for (int t = 0; t < 4; ++t) {
            x[t][0] = bcast(xd, t*2);
            x[t][1] = bcast(xd, t*2 + 1);
        }
    }
}

// ---------------------------------------------------------------------------
// K2: pick best step (first-occurrence argmin vs lb=1000), single thread
// ---------------------------------------------------------------------------
__global__ void k_pick(const int* __restrict__ nsp,
                       const float* __restrict__ lossacc, int* __restrict__ best)
{
    if (threadIdx.x == 0 && blockIdx.x == 0) {
        int ns = *nsp; if (ns > NSMAX) ns = NSMAX;
        float lb = 1000.f; int bi = -1;
        for (int s = 0; s < ns; ++s) {
            float loss = -lossacc[s] * (1.f / 16384.f);
            if (loss < lb) { lb = loss; bi = s; }
        }
        best[0] = bi;
    }
}

// ---------------------------------------------------------------------------
// K3: final forward flow from x_best, write y
// ---------------------------------------------------------------------------
__global__ __launch_bounds__(512) void k_final(
    const float* __restrict__ bs,
    const float* __restrict__ wih, const float* __restrict__ whh,
    const float* __restrict__ bih, const float* __restrict__ bhh,
    const float* __restrict__ Wl1, const float* __restrict__ bl1,
    const float* __restrict__ Wl2, const float* __restrict__ bl2,
    const float* __restrict__ z0ws, const float* __restrict__ traj,
    const int* __restrict__ best, float* __restrict__ out)
{
    __shared__ float smem[14472];
    const int tid = threadIdx.x, lane = tid & 63, w = tid >> 6;
    const int b = blockIdx.x * 8 + w;
    float* swT  = smem;
    float* swl1 = smem + 12352;
    for (int i = tid; i < 12288; i += 512) {
        int k = i / 192, c = i - k*192;
        swT[k*193 + c] = whh[c*64 + k];
    }
    for (int i = tid; i < 2048; i += 512) {
        int k = i >> 5, c = i & 31;
        swl1[k*33 + c] = Wl1[i];
    }
    __syncthreads();

    const int il = lane & 31;
    float wr0 = wih[lane*2],       wr1 = wih[lane*2+1];
    float wu0 = wih[(64+lane)*2],  wu1 = wih[(64+lane)*2+1];
    float wn0 = wih[(128+lane)*2], wn1 = wih[(128+lane)*2+1];
    float br = bih[lane], bu = bih[64+lane], bn = bih[128+lane];
    float hr = bhh[lane], hu = bhh[64+lane], hn = bhh[128+lane];
    float w2a = Wl2[il*4], w2b = Wl2[il*4+1], w2c = Wl2[il*4+2], w2d = Wl2[il*4+3];
    float b1r = bl1[il];
    float b20 = bl2[0], b21 = bl2[1], b22 = bl2[2], b23 = bl2[3];

    int bi = best[0];
    float xd = 0.f;
    if (lane < 8)
        xd = (bi >= 0) ? traj[((size_t)b*NSMAX + bi)*8 + lane] : bs[lane];
    float x[4][2];
    #pragma unroll
    for (int t = 0; t < 4; ++t) {
        x[t][0] = bcast(xd, t*2);
        x[t][1] = bcast(xd, t*2 + 1);
    }
    float zc = z0ws[(size_t)b*64 + lane];
    float y0 = 0.f, y1 = 0.f;
    float yv[4][2];
    #pragma unroll
    for (int t = 0; t < 4; ++t) {
        float gir = fmaf(wr0, y0, fmaf(wr1, y1, br));
        float giu = fmaf(wu0, y0, fmaf(wu1, y1, bu));
        float gin = fmaf(wn0, y0, fmaf(wn1, y1, bn));
        float ghr = hr, ghu = hu, ghn = hn;
        #pragma unroll 8
        for (int kk = 0; kk < 64; ++kk) {
            float zk = bcast(zc, kk);
            const float* wp = swT + kk*193 + lane;
            ghr = fmaf(wp[0],   zk, ghr);
            ghu = fmaf(wp[64],  zk, ghu);
            ghn = fmaf(wp[128], zk, ghn);
        }
        float r = sigmoidf(gir + ghr);
        float u = sigmoidf(giu + ghu);
        float n = tanhf(fmaf(r, ghn, gin));
        zc = fmaf(u, zc - n, n);
        float pre = 0.f;
        #pragma unroll 8
        for (int kk = 0; kk < 64; ++kk)
            pre = fmaf(swl1[kk*33 + il], bcast(zc, kk), pre);
        float a = fmaxf(pre + b1r, 0.f);
        float c0 = redsum64(a * w2a) * 0.5f + b20;
        float c1 = redsum64(a * w2b) * 0.5f + b21;
        float c2 = redsum64(a * w2c) * 0.5f + b22;
        float c3 = redsum64(a * w2d) * 0.5f + b23;
        float s0 = softplusf(c2) + 0.001f;
        float s1 = softplusf(c3) + 0.001f;
        y0 += c0 + s0 * x[t][0];
        y1 += c1 + s1 * x[t][1];
        yv[t][0] = y0; yv[t][1] = y1;
    }
    if (lane < 8)
        out[(size_t)b*8 + lane] = sel8(yv[0][0], yv[0][1], yv[1][0], yv[1][1],
                                       yv[2][0], yv[2][1], yv[3][0], yv[3][1], lane);
}

// ---------------------------------------------------------------------------
extern "C" void kernel_launch(void* const* d_in, const int* in_sizes, int n_in,
                              void* d_out, int out_size, void* d_ws, size_t ws_size,
                              hipStream_t stream)
{
    const float* visual = (const float*)d_in[0];
    const float* vel    = (const float*)d_in[1];
    const float* tl     = (const float*)d_in[2];
    const float* tls    = (const float*)d_in[3];
    const float* goal   = (const float*)d_in[4];
    const float* bs     = (const float*)d_in[5];
    const float* Wm1    = (const float*)d_in[6];
    const float* bm1    = (const float*)d_in[7];
    const float* Wm2    = (const float*)d_in[8];
    const float* bm2    = (const float*)d_in[9];
    const float* Wm3    = (const float*)d_in[10];
    const float* bm3    = (const float*)d_in[11];
    const float* wih    = (const float*)d_in[12];
    const float* whh    = (const float*)d_in[13];
    const float* bih    = (const float*)d_in[14];
    const float* bhh    = (const float*)d_in[15];
    const float* Wl1    = (const float*)d_in[16];
    const float* bl1    = (const float*)d_in[17];
    const float* Wl2    = (const float*)d_in[18];
    const float* bl2    = (const float*)d_in[19];
    const int*   nsp    = (const int*)d_in[20];

    float* z0ws    = (float*)d_ws;                          // B*64
    float* traj    = z0ws + (size_t)BATCH * 64;             // B*NSMAX*8
    float* lossacc = traj + (size_t)BATCH * NSMAX * 8;      // NSMAX
    int*   best    = (int*)(lossacc + NSMAX);               // 1

    hipMemsetAsync(lossacc, 0, NSMAX * sizeof(float), stream);

    k_adam<<<BATCH/8, 512, 0, stream>>>(
        visual, vel, tl, tls, goal, bs,
        Wm1, bm1, Wm2, bm2, Wm3, bm3,
        wih, whh, bih, bhh, Wl1, bl1, Wl2, bl2,
        nsp, z0ws, traj, lossacc);

    k_pick<<<1, 64, 0, stream>>>(nsp, lossacc, best);

    k_final<<<BATCH/8, 512, 0, stream>>>(
        bs, wih, whh, bih, bhh, Wl1, bl1, Wl2, bl2,
        z0ws, traj, best, (float*)d_out);
}

// Round 3
// 1185.507 us; speedup vs baseline: 1.3584x; 1.3584x over previous
//
#include <hip/hip_runtime.h>
#include <math.h>

#define BATCH 16384
#define NSMAX 8
#define LOG2PI_F 1.8378770664093453f
#define LOG4_F 1.3862943611198906f

typedef _Float16 v8h __attribute__((ext_vector_type(8)));
typedef float    v4f __attribute__((ext_vector_type(4)));
typedef float    v2f __attribute__((ext_vector_type(2)));

#define MFMA16(A,B,C) __builtin_amdgcn_mfma_f32_16x16x32_f16(A,B,C,0,0,0)

__device__ __forceinline__ float bcast(float v, int l) {
    return __uint_as_float(__builtin_amdgcn_readlane(__float_as_uint(v), (unsigned)l));
}
__device__ __forceinline__ float fsigm(float v){ return 1.f/(1.f + __expf(-v)); }
__device__ __forceinline__ float ftanh(float v){ return 1.f - 2.f/(__expf(2.f*v)+1.f); }
__device__ __forceinline__ float fsp(float v){ return fmaxf(v,0.f) + __logf(1.f + __expf(-fabsf(v))); }

// high/low fp16 split loads: v = (float)hi + (float)lo to ~2^-22 rel
__device__ __forceinline__ v8h ld8(const float* p){
    v4f a = *(const v4f*)p; v4f b = *(const v4f*)(p+4);
    v8h r;
    r[0]=(_Float16)a[0]; r[1]=(_Float16)a[1]; r[2]=(_Float16)a[2]; r[3]=(_Float16)a[3];
    r[4]=(_Float16)b[0]; r[5]=(_Float16)b[1]; r[6]=(_Float16)b[2]; r[7]=(_Float16)b[3];
    return r;
}
__device__ __forceinline__ v8h ld8lo(const float* p){
    v4f a = *(const v4f*)p; v4f b = *(const v4f*)(p+4);
    v8h r;
    #pragma unroll
    for (int j=0;j<4;++j){ _Float16 h=(_Float16)a[j]; r[j]=(_Float16)(a[j]-(float)h); }
    #pragma unroll
    for (int j=0;j<4;++j){ _Float16 h=(_Float16)b[j]; r[4+j]=(_Float16)(b[j]-(float)h); }
    return r;
}
__device__ __forceinline__ v8h ld8s(const float* p, int stride){
    v8h r;
    #pragma unroll
    for (int j=0;j<8;++j) r[j] = (_Float16)p[j*stride];
    return r;
}
__device__ __forceinline__ v8h ld8slo(const float* p, int stride){
    v8h r;
    #pragma unroll
    for (int j=0;j<8;++j){ float v=p[j*stride]; _Float16 h=(_Float16)v; r[j]=(_Float16)(v-(float)h); }
    return r;
}

// ---------------------------------------------------------------------------
// K0: MLP -> z0 (fp32 scalar, proven round-1 code)
// ---------------------------------------------------------------------------
__global__ __launch_bounds__(512) void k_mlp(
    const float* __restrict__ visual, const float* __restrict__ vel,
    const float* __restrict__ tl, const float* __restrict__ tls,
    const float* __restrict__ Wm1, const float* __restrict__ bm1,
    const float* __restrict__ Wm2, const float* __restrict__ bm2,
    const float* __restrict__ Wm3, const float* __restrict__ bm3,
    float* __restrict__ z0ws)
{
    __shared__ float smem[9600];
    const int tid  = threadIdx.x;
    const int lane = tid & 63;
    const int w    = tid >> 6;
    const int b    = blockIdx.x * 8 + w;
    for (int i = tid; i < 8512; i += 512) smem[i] = Wm1[i];
    float* sfeat = smem + 8512 + w * 136;
    sfeat[lane]      = visual[b*128 + lane];
    sfeat[64 + lane] = visual[b*128 + 64 + lane];
    if (lane < 3)  sfeat[128 + lane] = vel[b*3 + lane];
    if (lane == 3) sfeat[131] = tl[b];
    if (lane == 4) sfeat[132] = tls[b];
    __syncthreads();
    float acc = bm1[lane];
    for (int f = 0; f < 133; ++f) acc = fmaf(smem[f*64 + lane], sfeat[f], acc);
    float z1 = fmaxf(acc, 0.f);
    __syncthreads();
    for (int i = tid; i < 4096; i += 512) smem[i] = Wm2[i];
    __syncthreads();
    acc = bm2[lane];
    #pragma unroll 8
    for (int kk = 0; kk < 64; ++kk) acc = fmaf(smem[kk*64 + lane], bcast(z1, kk), acc);
    float z2 = fmaxf(acc, 0.f);
    __syncthreads();
    for (int i = tid; i < 4096; i += 512) smem[i] = Wm3[i];
    __syncthreads();
    acc = bm3[lane];
    #pragma unroll 8
    for (int kk = 0; kk < 64; ++kk) acc = fmaf(smem[kk*64 + lane], bcast(z2, kk), acc);
    z0ws[(size_t)b*64 + lane] = fmaxf(acc, 0.f);
}

// ---------------------------------------------------------------------------
// K1: MFMA flow with split-fp16 forward (~fp32 precision), fp16 backward.
// wave = 16 elements, block = 4 waves, grid = 256.
// Stage row per element (stride 200 halfs): [zh 0..63][zl 64..127][ab 128..159]
// bwd dgates reuse cols 0..191.
// ---------------------------------------------------------------------------
__global__ __launch_bounds__(256, 1) void k_adam(
    const float* __restrict__ goal, const float* __restrict__ bs,
    const float* __restrict__ wih, const float* __restrict__ whh,
    const float* __restrict__ bih, const float* __restrict__ bhh,
    const float* __restrict__ Wl1, const float* __restrict__ bl1,
    const float* __restrict__ Wl2, const float* __restrict__ bl2,
    const int*  __restrict__ nsp, const float* __restrict__ z0ws,
    float* __restrict__ traj, float* __restrict__ parts)
{
    __shared__ _Float16 whhT[64*200];      // whhT[j][c] = whh[c][j] (bwd dh B-frags)
    __shared__ _Float16 stg[4][16*200];    // per-wave staging
    __shared__ float    xs[4][16*20];      // per-wave x (0..7) / xbar (8..15)

    const int tid  = threadIdx.x;
    const int w    = tid >> 6;
    const int ln   = tid & 63;
    const int col  = ln & 15;
    const int quad = ln >> 4;
    const int b0   = blockIdx.x*64 + w*16;
    _Float16* sw = stg[w];

    for (int i = tid; i < 192*64; i += 256){
        int c = i >> 6, h = i & 63;
        whhT[h*200 + c] = (_Float16)whh[i];
    }
    __syncthreads();

    // ---- weight fragments ----
    v8h bwh[12][2], bwlo[12][2];   // GRU B: B[k=h][n=c], hi+lo split
    #pragma unroll
    for (int T=0;T<12;++T){
        int c = col + 16*T;
        bwh[T][0]  = ld8  (whh + c*64 +      quad*8);
        bwh[T][1]  = ld8  (whh + c*64 + 32 + quad*8);
        bwlo[T][0] = ld8lo(whh + c*64 +      quad*8);
        bwlo[T][1] = ld8lo(whh + c*64 + 32 + quad*8);
    }
    v8h w1h[2][2], w1l[2][2];      // Wl1 B: B[k=h][n=i], hi+lo
    #pragma unroll
    for (int T=0;T<2;++T){
        int n = col + 16*T;
        w1h[T][0] = ld8s  (Wl1 + (     quad*8)*32 + n, 32);
        w1h[T][1] = ld8s  (Wl1 + (32 + quad*8)*32 + n, 32);
        w1l[T][0] = ld8slo(Wl1 + (     quad*8)*32 + n, 32);
        w1l[T][1] = ld8slo(Wl1 + (32 + quad*8)*32 + n, 32);
    }
    v8h awl1[4];                   // bwd dz B: B[k=i][n=j] = Wl1[j][i]
    #pragma unroll
    for (int Tz=0;Tz<4;++Tz)
        awl1[Tz] = ld8(Wl1 + (col+16*Tz)*32 + quad*8);

    float wi0[12], wi1[12], bihv[12], bhhv[12];
    #pragma unroll
    for (int T=0;T<12;++T){
        int c = col + 16*T;
        wi0[T] = wih[c*2]; wi1[T] = wih[c*2+1];
        bihv[T] = bih[c];  bhhv[T] = bhh[c];
    }
    float w2[2][4], bl1v[2];
    #pragma unroll
    for (int T=0;T<2;++T){
        int i5 = col + 16*T;
        bl1v[T] = bl1[i5];
        #pragma unroll
        for (int j=0;j<4;++j) w2[T][j] = Wl2[i5*4+j];
    }
    float b2[4] = {bl2[0], bl2[1], bl2[2], bl2[3]};

    // ---- z0 registers (C-layout: h=col+16Tz, e=quad*4+r) ----
    float zc[4][4], zck[4][4][4];
    #pragma unroll
    for (int Tz=0;Tz<4;++Tz)
        #pragma unroll
        for (int r=0;r<4;++r){
            float v = z0ws[(size_t)(b0+quad*4+r)*64 + col + 16*Tz];
            zc[Tz][r] = v; zck[0][Tz][r] = v;
        }

    // ---- x init: lane owns (e=col, dims 2*quad, 2*quad+1) ----
    float xa0 = bs[2*quad], xa1 = bs[2*quad+1];
    xs[w][col*20 + 2*quad]   = xa0;
    xs[w][col*20 + 2*quad+1] = xa1;
    float am0=0,am1=0,av0=0,av1=0,pb1=1.f,pb2=1.f;

    int ns = *nsp; if (ns > NSMAX) ns = NSMAX;

    float rg[4][4], ug[4][4], ngv[4][4], ghs[4][4], aa[2][4];
    float s0v[4], s1v[4], c0v[4], c1v[4];

    // split-stage zc into [zh | zl]
    auto stage_z = [&](const float (&z)[4][4]){
        #pragma unroll
        for (int Tz=0;Tz<4;++Tz)
            #pragma unroll
            for (int r=0;r<4;++r){
                float v = z[Tz][r];
                _Float16 h = (_Float16)v;
                int o = (quad*4+r)*200 + col + 16*Tz;
                sw[o] = h; sw[o+64] = (_Float16)(v-(float)h);
            }
    };
    // 3-term split GEMM accumulate
    auto z3 = [&](v8h ah0, v8h ah1, v8h al0, v8h al1, const v8h* Bh, const v8h* Bl) -> v4f {
        v4f acc = {0.f,0.f,0.f,0.f};
        acc = MFMA16(ah0, Bl[0], acc);
        acc = MFMA16(ah1, Bl[1], acc);
        acc = MFMA16(al0, Bh[0], acc);
        acc = MFMA16(al1, Bh[1], acc);
        acc = MFMA16(ah0, Bh[0], acc);
        acc = MFMA16(ah1, Bh[1], acc);
        return acc;
    };

    // GRU cell + heads. Precondition: stage holds split of current zc.
    auto cell = [&](const float (&yp0)[4], const float (&yp1)[4]){
        v8h ah0 = *(const v8h*)(sw + col*200 +      quad*8);
        v8h ah1 = *(const v8h*)(sw + col*200 + 32 + quad*8);
        v8h al0 = *(const v8h*)(sw + col*200 + 64 + quad*8);
        v8h al1 = *(const v8h*)(sw + col*200 + 96 + quad*8);
        #pragma unroll
        for (int Tz=0;Tz<4;++Tz){
            v4f gr = z3(ah0,ah1,al0,al1, bwh[Tz],   bwlo[Tz]);
            v4f gu = z3(ah0,ah1,al0,al1, bwh[Tz+4], bwlo[Tz+4]);
            v4f gn = z3(ah0,ah1,al0,al1, bwh[Tz+8], bwlo[Tz+8]);
            #pragma unroll
            for (int r=0;r<4;++r){
                float pr = gr[r] + wi0[Tz]*yp0[r]   + wi1[Tz]*yp1[r]   + bihv[Tz]   + bhhv[Tz];
                float pu = gu[r] + wi0[Tz+4]*yp0[r] + wi1[Tz+4]*yp1[r] + bihv[Tz+4] + bhhv[Tz+4];
                float gh = gn[r] + bhhv[Tz+8];
                float gi = wi0[Tz+8]*yp0[r] + wi1[Tz+8]*yp1[r] + bihv[Tz+8];
                float R = fsigm(pr), U = fsigm(pu);
                float N = ftanh(gi + R*gh);
                rg[Tz][r]=R; ug[Tz][r]=U; ngv[Tz][r]=N; ghs[Tz][r]=gh;
                zc[Tz][r] = (1.f-U)*N + U*zc[Tz][r];
            }
        }
        stage_z(zc);
        v8h bh0 = *(const v8h*)(sw + col*200 +      quad*8);
        v8h bh1 = *(const v8h*)(sw + col*200 + 32 + quad*8);
        v8h bl0 = *(const v8h*)(sw + col*200 + 64 + quad*8);
        v8h blf = *(const v8h*)(sw + col*200 + 96 + quad*8);
        #pragma unroll
        for (int T=0;T<2;++T){
            v4f acc = {0.f,0.f,0.f,0.f};
            acc = MFMA16(bh0, w1l[T][0], acc);
            acc = MFMA16(bh1, w1l[T][1], acc);
            acc = MFMA16(bl0, w1h[T][0], acc);
            acc = MFMA16(blf, w1h[T][1], acc);
            acc = MFMA16(bh0, w1h[T][0], acc);
            acc = MFMA16(bh1, w1h[T][1], acc);
            #pragma unroll
            for (int r=0;r<4;++r) aa[T][r] = fmaxf(acc[r] + bl1v[T], 0.f);
        }
        #pragma unroll
        for (int r=0;r<4;++r){
            float q0 = aa[0][r]*w2[0][0] + aa[1][r]*w2[1][0];
            float q1 = aa[0][r]*w2[0][1] + aa[1][r]*w2[1][1];
            float q2 = aa[0][r]*w2[0][2] + aa[1][r]*w2[1][2];
            float q3 = aa[0][r]*w2[0][3] + aa[1][r]*w2[1][3];
            #pragma unroll
            for (int m=1;m<16;m<<=1){
                q0 += __shfl_xor(q0,m); q1 += __shfl_xor(q1,m);
                q2 += __shfl_xor(q2,m); q3 += __shfl_xor(q3,m);
            }
            c0v[r] = q0 + b2[0]; c1v[r] = q1 + b2[1];
            s0v[r] = fsp(q2 + b2[2]) + 0.001f;
            s1v[r] = fsp(q3 + b2[3]) + 0.001f;
        }
    };

    for (int s=0; s<ns; ++s){
        // reset z to z0
        #pragma unroll
        for (int Tz=0;Tz<4;++Tz)
            #pragma unroll
            for (int r=0;r<4;++r) zc[Tz][r] = zck[0][Tz][r];
        stage_z(zc);
        // ---------- forward ----------
        float y0[4]={0,0,0,0}, y1[4]={0,0,0,0};
        float ys0[4][4], ys1[4][4], sumls[4]={0,0,0,0}, sumx2[4]={0,0,0,0};
        #pragma unroll
        for (int t=0;t<4;++t){
            cell(y0, y1);
            #pragma unroll
            for (int r=0;r<4;++r){
                v2f xv = *(const v2f*)(&xs[w][(quad*4+r)*20 + 2*t]);
                sumx2[r] += xv[0]*xv[0] + xv[1]*xv[1];
                y0[r] += c0v[r] + s0v[r]*xv[0];
                y1[r] += c1v[r] + s1v[r]*xv[1];
                ys0[t][r]=y0[r]; ys1[t][r]=y1[r];
                sumls[r] += __logf(s0v[r]) + __logf(s1v[r]);
            }
            if (t<3){
                #pragma unroll
                for (int Tz=0;Tz<4;++Tz)
                    #pragma unroll
                    for (int r=0;r<4;++r) zck[t+1][Tz][r] = zc[Tz][r];
            }
        }
        // ---------- loss + y-grad ----------
        float cel[4], yb0[4], yb1[4];
        #pragma unroll
        for (int r=0;r<4;++r){
            const float* gpt = goal + (size_t)(b0+quad*4+r)*8;
            v4f ga = *(const v4f*)gpt; v4f gb = *(const v4f*)(gpt+4);
            float c0_ = -0.5f*((y0[r]-ga[0])*(y0[r]-ga[0]) + (y1[r]-ga[1])*(y1[r]-ga[1])) - LOG2PI_F;
            float c1_ = -0.5f*((y0[r]-ga[2])*(y0[r]-ga[2]) + (y1[r]-ga[3])*(y1[r]-ga[3])) - LOG2PI_F;
            float c2_ = -0.5f*((y0[r]-gb[0])*(y0[r]-gb[0]) + (y1[r]-gb[1])*(y1[r]-gb[1])) - LOG2PI_F;
            float c3_ = -0.5f*((y0[r]-gb[2])*(y0[r]-gb[2]) + (y1[r]-gb[3])*(y1[r]-gb[3])) - LOG2PI_F;
            float mx = fmaxf(fmaxf(c0_,c1_), fmaxf(c2_,c3_));
            float e0 = __expf(c0_-mx), e1 = __expf(c1_-mx), e2 = __expf(c2_-mx), e3 = __expf(c3_-mx);
            float se = e0+e1+e2+e3;
            float lp = mx + __logf(se) - LOG4_F;
            cel[r] = -0.5f*sumx2[r] - 4.f*LOG2PI_F - sumls[r] + lp;
            float inv = 1.f/se;
            yb0[r] = inv*(e0*(ga[0]-y0[r]) + e1*(ga[2]-y0[r]) + e2*(gb[0]-y0[r]) + e3*(gb[2]-y0[r]));
            yb1[r] = inv*(e0*(ga[1]-y1[r]) + e1*(ga[3]-y1[r]) + e2*(gb[1]-y1[r]) + e3*(gb[3]-y1[r]));
        }
        float tsum = cel[0]+cel[1]+cel[2]+cel[3];
        tsum += __shfl_xor(tsum,16); tsum += __shfl_xor(tsum,32);
        if (ln==0) parts[s*1024 + blockIdx.x*4 + w] = tsum;

        // ---------- backward (fp16 GEMMs; gates recomputed w/ split) ----------
        float zbN[4][4];
        #pragma unroll
        for (int Tz=0;Tz<4;++Tz){ zbN[Tz][0]=0;zbN[Tz][1]=0;zbN[Tz][2]=0;zbN[Tz][3]=0; }
        #pragma unroll
        for (int tt=0; tt<4; ++tt){
            const int t = 3-tt;
            #pragma unroll
            for (int Tz=0;Tz<4;++Tz)
                #pragma unroll
                for (int r=0;r<4;++r) zc[Tz][r] = zck[t][Tz][r];
            stage_z(zc);
            float yp0[4], yp1[4];
            #pragma unroll
            for (int r=0;r<4;++r){
                yp0[r] = (t==0) ? 0.f : ys0[t-1][r];
                yp1[r] = (t==0) ? 0.f : ys1[t-1][r];
            }
            cell(yp0, yp1);   // recompute gates at t (zck[t] intact in regs)

            float l2[4], l3[4];
            #pragma unroll
            for (int r=0;r<4;++r){
                v2f xv = *(const v2f*)(&xs[w][(quad*4+r)*20 + 2*t]);
                float sb0 = yb0[r]*xv[0] - 1.f/s0v[r];
                float sb1 = yb1[r]*xv[1] - 1.f/s1v[r];
                float sg0 = 1.f - __expf(-(s0v[r]-0.001f));
                float sg1 = 1.f - __expf(-(s1v[r]-0.001f));
                l2[r] = sb0*sg0; l3[r] = sb1*sg1;
                v2f xb; xb[0] = yb0[r]*s0v[r] - xv[0]; xb[1] = yb1[r]*s1v[r] - xv[1];
                *(v2f*)(&xs[w][(quad*4+r)*20 + 8 + 2*t]) = xb;
            }
            // ab -> stage cols 128..159
            #pragma unroll
            for (int T=0;T<2;++T)
                #pragma unroll
                for (int r=0;r<4;++r){
                    float ab = w2[T][0]*yb0[r] + w2[T][1]*yb1[r] + w2[T][2]*l2[r] + w2[T][3]*l3[r];
                    ab = (aa[T][r] > 0.f) ? ab : 0.f;
                    sw[(quad*4+r)*200 + 128 + col + 16*T] = (_Float16)ab;
                }
            // dzt = zbN + ab @ Wl1^T  (direct C-layout, seeded with carry)
            v8h a_ab = *(const v8h*)(sw + col*200 + 128 + quad*8);
            float dzt[4][4];
            #pragma unroll
            for (int Tz=0;Tz<4;++Tz){
                v4f acc = { zbN[Tz][0], zbN[Tz][1], zbN[Tz][2], zbN[Tz][3] };
                acc = MFMA16(a_ab, awl1[Tz], acc);
                #pragma unroll
                for (int r=0;r<4;++r) dzt[Tz][r] = acc[r];
            }
            // dgates -> stage cols 0..191
            float drp[4][4], dup[4][4], dnp[4][4];
            #pragma unroll
            for (int Tz=0;Tz<4;++Tz)
                #pragma unroll
                for (int r=0;r<4;++r){
                    float U=ug[Tz][r], N=ngv[Tz][r], R=rg[Tz][r], GH=ghs[Tz][r];
                    float nb = dzt[Tz][r]*(1.f-U);
                    float dn = nb*(1.f-N*N);
                    dnp[Tz][r] = dn;
                    float gnb = dn*R;
                    float rb  = dn*GH;
                    drp[Tz][r] = rb*R*(1.f-R);
                    dup[Tz][r] = dzt[Tz][r]*(zck[t][Tz][r]-N)*U*(1.f-U);
                    int o = (quad*4+r)*200 + col + 16*Tz;
                    sw[o]       = (_Float16)drp[Tz][r];
                    sw[o + 64]  = (_Float16)dup[Tz][r];
                    sw[o + 128] = (_Float16)gnb;
                }
            // zbN = dg @ whh + dzt*u  (direct C-layout, seeded)
            v8h adg[6];
            #pragma unroll
            for (int kc=0;kc<6;++kc)
                adg[kc] = *(const v8h*)(sw + col*200 + kc*32 + quad*8);
            #pragma unroll
            for (int Tz=0;Tz<4;++Tz){
                v4f acc = { dzt[Tz][0]*ug[Tz][0], dzt[Tz][1]*ug[Tz][1],
                            dzt[Tz][2]*ug[Tz][2], dzt[Tz][3]*ug[Tz][3] };
                #pragma unroll
                for (int kc=0;kc<6;++kc){
                    v8h bwt = *(const v8h*)(whhT + (col+16*Tz)*200 + kc*32 + quad*8);
                    acc = MFMA16(adg[kc], bwt, acc);
                }
                #pragma unroll
                for (int r=0;r<4;++r) zbN[Tz][r] = acc[r];
            }
            // y-grad propagation (fp32)
            #pragma unroll
            for (int r=0;r<4;++r){
                float px0 = 0.f, px1 = 0.f;
                #pragma unroll
                for (int Tz=0;Tz<4;++Tz){
                    px0 += drp[Tz][r]*wi0[Tz] + dup[Tz][r]*wi0[Tz+4] + dnp[Tz][r]*wi0[Tz+8];
                    px1 += drp[Tz][r]*wi1[Tz] + dup[Tz][r]*wi1[Tz+4] + dnp[Tz][r]*wi1[Tz+8];
                }
                #pragma unroll
                for (int m=1;m<16;m<<=1){ px0 += __shfl_xor(px0,m); px1 += __shfl_xor(px1,m); }
                yb0[r] += px0; yb1[r] += px1;
            }
        }
        // ---------- Adam (lane owns e=col, dims 2*quad..+1) ----------
        v2f xb = *(const v2f*)(&xs[w][col*20 + 8 + 2*quad]);
        float g0 = xb[0] * (-1.f/16384.f), g1 = xb[1] * (-1.f/16384.f);
        am0 = 0.9f*am0 + 0.1f*g0;        am1 = 0.9f*am1 + 0.1f*g1;
        av0 = 0.999f*av0 + 0.001f*g0*g0; av1 = 0.999f*av1 + 0.001f*g1*g1;
        pb1 *= 0.9f; pb2 *= 0.999f;
        float ic1 = 1.f/(1.f-pb1), ic2 = 1.f/(1.f-pb2);
        xa0 -= 0.1f*(am0*ic1)/(sqrtf(av0*ic2) + 1e-8f);
        xa1 -= 0.1f*(am1*ic1)/(sqrtf(av1*ic2) + 1e-8f);
        xs[w][col*20 + 2*quad]   = xa0;
        xs[w][col*20 + 2*quad+1] = xa1;
        v2f tv; tv[0]=xa0; tv[1]=xa1;
        *(v2f*)(traj + (size_t)(b0+col)*64 + s*8 + 2*quad) = tv;
    }
}

// ---------------------------------------------------------------------------
// K2: pick best step (deterministic reduction over partials)
// ---------------------------------------------------------------------------
__global__ void k_pick(const int* __restrict__ nsp,
                       const float* __restrict__ parts, int* __restrict__ best)
{
    int ln = threadIdx.x & 63;
    int ns = *nsp; if (ns > NSMAX) ns = NSMAX;
    float losses[NSMAX];
    for (int s=0;s<NSMAX;++s){
        float acc = 0.f;
        if (s < ns){
            for (int i=ln;i<1024;i+=64) acc += parts[s*1024+i];
            #pragma unroll
            for (int m=1;m<64;m<<=1) acc += __shfl_xor(acc,m);
        }
        losses[s] = -acc * (1.f/16384.f);
    }
    if (ln==0 && blockIdx.x==0){
        float lb = 1000.f; int bi = -1;
        for (int s=0;s<ns;++s) if (losses[s] < lb){ lb = losses[s]; bi = s; }
        best[0] = bi;
    }
}

// ---------------------------------------------------------------------------
// K3: final forward from x_best (split-fp16 MFMA, fwd-only)
// ---------------------------------------------------------------------------
__global__ __launch_bounds__(256, 1) void k_final(
    const float* __restrict__ bs,
    const float* __restrict__ wih, const float* __restrict__ whh,
    const float* __restrict__ bih, const float* __restrict__ bhh,
    const float* __restrict__ Wl1, const float* __restrict__ bl1,
    const float* __restrict__ Wl2, const float* __restrict__ bl2,
    const float* __restrict__ z0ws, const float* __restrict__ traj,
    const int* __restrict__ best, float* __restrict__ outp)
{
    __shared__ _Float16 stg[4][16*200];
    __shared__ float    xs[4][16*20];

    const int tid  = threadIdx.x;
    const int w    = tid >> 6;
    const int ln   = tid & 63;
    const int col  = ln & 15;
    const int quad = ln >> 4;
    const int b0   = blockIdx.x*64 + w*16;
    _Float16* sw = stg[w];

    v8h bwh[12][2], bwlo[12][2];
    #pragma unroll
    for (int T=0;T<12;++T){
        int c = col + 16*T;
        bwh[T][0]  = ld8  (whh + c*64 +      quad*8);
        bwh[T][1]  = ld8  (whh + c*64 + 32 + quad*8);
        bwlo[T][0] = ld8lo(whh + c*64 +      quad*8);
        bwlo[T][1] = ld8lo(whh + c*64 + 32 + quad*8);
    }
    v8h w1h[2][2], w1l[2][2];
    #pragma unroll
    for (int T=0;T<2;++T){
        int n = col + 16*T;
        w1h[T][0] = ld8s  (Wl1 + (     quad*8)*32 + n, 32);
        w1h[T][1] = ld8s  (Wl1 + (32 + quad*8)*32 + n, 32);
        w1l[T][0] = ld8slo(Wl1 + (     quad*8)*32 + n, 32);
        w1l[T][1] = ld8slo(Wl1 + (32 + quad*8)*32 + n, 32);
    }
    float wi0[12], wi1[12], bihv[12], bhhv[12];
    #pragma unroll
    for (int T=0;T<12;++T){
        int c = col + 16*T;
        wi0[T] = wih[c*2]; wi1[T] = wih[c*2+1];
        bihv[T] = bih[c];  bhhv[T] = bhh[c];
    }
    float w2[2][4], bl1v[2];
    #pragma unroll
    for (int T=0;T<2;++T){
        int i5 = col + 16*T;
        bl1v[T] = bl1[i5];
        #pragma unroll
        for (int j=0;j<4;++j) w2[T][j] = Wl2[i5*4+j];
    }
    float b2[4] = {bl2[0], bl2[1], bl2[2], bl2[3]};

    float zc[4][4];
    #pragma unroll
    for (int Tz=0;Tz<4;++Tz)
        #pragma unroll
        for (int r=0;r<4;++r)
            zc[Tz][r] = z0ws[(size_t)(b0+quad*4+r)*64 + col + 16*Tz];
    #pragma unroll
    for (int Tz=0;Tz<4;++Tz)
        #pragma unroll
        for (int r=0;r<4;++r){
            float v = zc[Tz][r];
            _Float16 h = (_Float16)v;
            int o = (quad*4+r)*200 + col + 16*Tz;
            sw[o] = h; sw[o+64] = (_Float16)(v-(float)h);
        }

    int bi = best[0];
    float x0i, x1i;
    if (bi >= 0){
        v2f xv = *(const v2f*)(traj + (size_t)(b0+col)*64 + bi*8 + 2*quad);
        x0i = xv[0]; x1i = xv[1];
    } else { x0i = bs[2*quad]; x1i = bs[2*quad+1]; }
    xs[w][col*20 + 2*quad]   = x0i;
    xs[w][col*20 + 2*quad+1] = x1i;

    float y0[4]={0,0,0,0}, y1[4]={0,0,0,0};
    float ys0[4][4], ys1[4][4];
    #pragma unroll
    for (int t=0;t<4;++t){
        v8h ah0 = *(const v8h*)(sw + col*200 +      quad*8);
        v8h ah1 = *(const v8h*)(sw + col*200 + 32 + quad*8);
        v8h al0 = *(const v8h*)(sw + col*200 + 64 + quad*8);
        v8h al1 = *(const v8h*)(sw + col*200 + 96 + quad*8);
        #pragma unroll
        for (int Tz=0;Tz<4;++Tz){
            v4f gr = {0,0,0,0}, gu = {0,0,0,0}, gn = {0,0,0,0};
            gr = MFMA16(ah0, bwlo[Tz][0], gr);   gr = MFMA16(ah1, bwlo[Tz][1], gr);
            gr = MFMA16(al0, bwh[Tz][0],  gr);   gr = MFMA16(al1, bwh[Tz][1],  gr);
            gr = MFMA16(ah0, bwh[Tz][0],  gr);   gr = MFMA16(ah1, bwh[Tz][1],  gr);
            gu = MFMA16(ah0, bwlo[Tz+4][0], gu); gu = MFMA16(ah1, bwlo[Tz+4][1], gu);
            gu = MFMA16(al0, bwh[Tz+4][0],  gu); gu = MFMA16(al1, bwh[Tz+4][1],  gu);
            gu = MFMA16(ah0, bwh[Tz+4][0],  gu); gu = MFMA16(ah1, bwh[Tz+4][1],  gu);
            gn = MFMA16(ah0, bwlo[Tz+8][0], gn); gn = MFMA16(ah1, bwlo[Tz+8][1], gn);
            gn = MFMA16(al0, bwh[Tz+8][0],  gn); gn = MFMA16(al1, bwh[Tz+8][1],  gn);
            gn = MFMA16(ah0, bwh[Tz+8][0],  gn); gn = MFMA16(ah1, bwh[Tz+8][1],  gn);
            #pragma unroll
            for (int r=0;r<4;++r){
                float pr = gr[r] + wi0[Tz]*y0[r]   + wi1[Tz]*y1[r]   + bihv[Tz]   + bhhv[Tz];
                float pu = gu[r] + wi0[Tz+4]*y0[r] + wi1[Tz+4]*y1[r] + bihv[Tz+4] + bhhv[Tz+4];
                float gh = gn[r] + bhhv[Tz+8];
                float gi = wi0[Tz+8]*y0[r] + wi1[Tz+8]*y1[r] + bihv[Tz+8];
                float R = fsigm(pr), U = fsigm(pu);
                float N = ftanh(gi + R*gh);
                zc[Tz][r] = (1.f-U)*N + U*zc[Tz][r];
            }
        }
        #pragma unroll
        for (int Tz=0;Tz<4;++Tz)
            #pragma unroll
            for (int r=0;r<4;++r){
                float v = zc[Tz][r];
                _Float16 h = (_Float16)v;
                int o = (quad*4+r)*200 + col + 16*Tz;
                sw[o] = h; sw[o+64] = (_Float16)(v-(float)h);
            }
        v8h bh0 = *(const v8h*)(sw + col*200 +      quad*8);
        v8h bh1 = *(const v8h*)(sw + col*200 + 32 + quad*8);
        v8h bl0 = *(const v8h*)(sw + col*200 + 64 + quad*8);
        v8h blf = *(const v8h*)(sw + col*200 + 96 + quad*8);
        float aaf[2][4];
        #pragma unroll
        for (int T=0;T<2;++T){
            v4f acc = {0.f,0.f,0.f,0.f};
            acc = MFMA16(bh0, w1l[T][0], acc);
            acc = MFMA16(bh1, w1l[T][1], acc);
            acc = MFMA16(bl0, w1h[T][0], acc);
            acc = MFMA16(blf, w1h[T][1], acc);
            acc = MFMA16(bh0, w1h[T][0], acc);
            acc = MFMA16(bh1, w1h[T][1], acc);
            #pragma unroll
            for (int r=0;r<4;++r) aaf[T][r] = fmaxf(acc[r] + bl1v[T], 0.f);
        }
        #pragma unroll
        for (int r=0;r<4;++r){
            float q0 = aaf[0][r]*w2[0][0] + aaf[1][r]*w2[1][0];
            float q1 = aaf[0][r]*w2[0][1] + aaf[1][r]*w2[1][1];
            float q2 = aaf[0][r]*w2[0][2] + aaf[1][r]*w2[1][2];
            float q3 = aaf[0][r]*w2[0][3] + aaf[1][r]*w2[1][3];
            #pragma unroll
            for (int m=1;m<16;m<<=1){
                q0 += __shfl_xor(q0,m); q1 += __shfl_xor(q1,m);
                q2 += __shfl_xor(q2,m); q3 += __shfl_xor(q3,m);
            }
            float c0 = q0 + b2[0], c1 = q1 + b2[1];
            float s0 = fsp(q2 + b2[2]) + 0.001f;
            float s1 = fsp(q3 + b2[3]) + 0.001f;
            v2f xv = *(const v2f*)(&xs[w][(quad*4+r)*20 + 2*t]);
            y0[r] += c0 + s0*xv[0];
            y1[r] += c1 + s1*xv[1];
            ys0[t][r]=y0[r]; ys1[t][r]=y1[r];
        }
    }
    if (col == 0){
        #pragma unroll
        for (int r=0;r<4;++r)
            #pragma unroll
            for (int t=0;t<4;++t){
                v2f o; o[0]=ys0[t][r]; o[1]=ys1[t][r];
                *(v2f*)(outp + (size_t)(b0+quad*4+r)*8 + 2*t) = o;
            }
    }
}

// ---------------------------------------------------------------------------
extern "C" void kernel_launch(void* const* d_in, const int* in_sizes, int n_in,
                              void* d_out, int out_size, void* d_ws, size_t ws_size,
                              hipStream_t stream)
{
    const float* visual = (const float*)d_in[0];
    const float* vel    = (const float*)d_in[1];
    const float* tl     = (const float*)d_in[2];
    const float* tls    = (const float*)d_in[3];
    const float* goal   = (const float*)d_in[4];
    const float* bs     = (const float*)d_in[5];
    const float* Wm1    = (const float*)d_in[6];
    const float* bm1    = (const float*)d_in[7];
    const float* Wm2    = (const float*)d_in[8];
    const float* bm2    = (const float*)d_in[9];
    const float* Wm3    = (const float*)d_in[10];
    const float* bm3    = (const float*)d_in[11];
    const float* wih    = (const float*)d_in[12];
    const float* whh    = (const float*)d_in[13];
    const float* bih    = (const float*)d_in[14];
    const float* bhh    = (const float*)d_in[15];
    const float* Wl1    = (const float*)d_in[16];
    const float* bl1    = (const float*)d_in[17];
    const float* Wl2    = (const float*)d_in[18];
    const float* bl2    = (const float*)d_in[19];
    const int*   nsp    = (const int*)d_in[20];

    float* z0ws  = (float*)d_ws;                     // B*64
    float* traj  = z0ws + (size_t)BATCH * 64;        // B*64
    float* parts = traj + (size_t)BATCH * 64;        // 8*1024
    int*   best  = (int*)(parts + NSMAX*1024);       // 1

    k_mlp<<<BATCH/8, 512, 0, stream>>>(visual, vel, tl, tls,
        Wm1, bm1, Wm2, bm2, Wm3, bm3, z0ws);

    k_adam<<<BATCH/64, 256, 0, stream>>>(goal, bs,
        wih, whh, bih, bhh, Wl1, bl1, Wl2, bl2,
        nsp, z0ws, traj, parts);

    k_pick<<<1, 64, 0, stream>>>(nsp, parts, best);

    k_final<<<BATCH/64, 256, 0, stream>>>(bs,
        wih, whh, bih, bhh, Wl1, bl1, Wl2, bl2,
        z0ws, traj, best, (float*)d_out);
}